// Round 5
// baseline (2977.612 us; speedup 1.0000x reference)
//
#include <hip/hip_runtime.h>
#include <hip/hip_bf16.h>
#include <math.h>

// B=2, N=4096, C=1024, HEADS=16, DH=64, BUCKET=64, N_HASHES=4, n_buckets=64
// BH=32, T=4096, 256 bins (r*64+b), 256 chunks of 64 slots per bh.
//
// ROUND 5: (prong A) discrete path replicates numpy-fp32 numerics:
//   qk = sequential fp32 FMA over k (BLAS sgemm per-element order),
//   rotated = sequential fp32 FMA over f (einsum order), fp32 argmax.
// (prong B) bucketing+sort replaced by independent implementations:
//   standalone bucket kernel + per-bh in-LDS bitonic sort on the exact
//   reference key bin*4096+token.

// ---------------------------------------------------------------------------
// Projection GEMM: C[m][n] = seqFMA_k A[m][k]*W[n][k] (+bias at end).
// Block: 256 threads = 256 n's; m-tile of 8 staged in LDS. Grid (1024, 4).
// Per-element k-order: ascending, single fp32 accumulator, FMA — mimics BLAS.
// ---------------------------------------------------------------------------
__global__ __launch_bounds__(256) void proj_gemm(const float* __restrict__ A,
                                                 const float* __restrict__ W,
                                                 float* __restrict__ out,
                                                 int headLayout,
                                                 const float* __restrict__ bias) {
    __shared__ float As[8][1024];
    int tid = threadIdx.x;
    int m0 = blockIdx.x * 8;
    int n = blockIdx.y * 256 + tid;

    for (int u = 0; u < 8; ++u) {
        int flat = u * 256 + tid;      // 2048 float4 units
        int r = flat >> 8;             // 0..7
        int c4 = (flat & 255) * 4;
        *(float4*)&As[r][c4] = *(const float4*)&A[(size_t)(m0 + r) * 1024 + c4];
    }
    __syncthreads();

    float acc[8];
#pragma unroll
    for (int j = 0; j < 8; ++j) acc[j] = 0.f;

    const float* wr = &W[(size_t)n * 1024];
    for (int k = 0; k < 1024; k += 4) {
        float4 w4 = *(const float4*)&wr[k];
#pragma unroll
        for (int j = 0; j < 8; ++j) acc[j] = fmaf(As[j][k + 0], w4.x, acc[j]);
#pragma unroll
        for (int j = 0; j < 8; ++j) acc[j] = fmaf(As[j][k + 1], w4.y, acc[j]);
#pragma unroll
        for (int j = 0; j < 8; ++j) acc[j] = fmaf(As[j][k + 2], w4.z, acc[j]);
#pragma unroll
        for (int j = 0; j < 8; ++j) acc[j] = fmaf(As[j][k + 3], w4.w, acc[j]);
    }

#pragma unroll
    for (int j = 0; j < 8; ++j) {
        int m = m0 + j;
        int bb = m >> 12, t = m & 4095;
        float val = acc[j];
        if (bias) val += bias[n];
        if (headLayout) {
            out[(((size_t)(bb * 16 + (n >> 6))) * 4096 + t) * 64 + (n & 63)] = val;
        } else {
            out[(size_t)m * 1024 + n] = val;
        }
    }
}

// ---------------------------------------------------------------------------
// Bucketing: one thread per (bh, r, token). rotated[i] = seqFMA_f qk[f]*R[f,r,i]
// in fp32; argmax over [rot, -rot] (first occurrence). Writes reference sort
// key = (r*64+bucket)*4096 + token at slot r*4096+token.
// ---------------------------------------------------------------------------
__global__ __launch_bounds__(256) void bucket32(const float* __restrict__ qk,
                                                const float* __restrict__ rot,
                                                int* __restrict__ keys) {
    int gid = blockIdx.x * 256 + threadIdx.x;   // 0..524287
    int token = gid & 4095;
    int r = (gid >> 12) & 3;
    int bh = gid >> 14;
    const float* q = &qk[((size_t)bh * 4096 + token) * 64];
    float racc[32];
#pragma unroll
    for (int i = 0; i < 32; ++i) racc[i] = 0.f;
    for (int f = 0; f < 64; ++f) {
        float qv = q[f];
        const float* rp = &rot[f * 128 + r * 32];
#pragma unroll
        for (int i = 0; i < 32; ++i) racc[i] = fmaf(qv, rp[i], racc[i]);
    }
    float best = -INFINITY;
    int bi = 0;
#pragma unroll
    for (int i = 0; i < 32; ++i) { if (racc[i] > best) { best = racc[i]; bi = i; } }
#pragma unroll
    for (int i = 0; i < 32; ++i) { float x = -racc[i]; if (x > best) { best = x; bi = 32 + i; } }
    int bin = r * 64 + bi;
    keys[(size_t)bh * 16384 + r * 4096 + token] = bin * 4096 + token;
}

// ---------------------------------------------------------------------------
// Bitonic sort of 16384 keys per bh in LDS (64 KiB). Ascending; keys unique.
// st_sorted[slot] = key & 4095 (original token). Grid 32, block 256.
// ---------------------------------------------------------------------------
__global__ __launch_bounds__(256) void bitonic_kernel(const int* __restrict__ keys,
                                                      int* __restrict__ st_sorted) {
    __shared__ int s[16384];
    int bh = blockIdx.x, tid = threadIdx.x;
    for (int u = 0; u < 64; ++u)
        s[u * 256 + tid] = keys[(size_t)bh * 16384 + u * 256 + tid];
    __syncthreads();
    for (int k = 2; k <= 16384; k <<= 1) {
        for (int j = k >> 1; j > 0; j >>= 1) {
            for (int u = 0; u < 64; ++u) {
                int i = u * 256 + tid;
                int ixj = i ^ j;
                if (ixj > i) {
                    int a = s[i], b2 = s[ixj];
                    bool up = ((i & k) == 0);
                    if ((a > b2) == up) { s[i] = b2; s[ixj] = a; }
                }
            }
            __syncthreads();
        }
    }
    for (int u = 0; u < 64; ++u) {
        int slot = u * 256 + tid;
        st_sorted[(size_t)bh * 16384 + slot] = s[slot] & 4095;
    }
}

// ---------------------------------------------------------------------------
// Brute-force chunked attention (exonerated in r3). Grid 8192 = 32 bh * 256
// chunks. Block 64 = one thread per query row.
// ---------------------------------------------------------------------------
__global__ __launch_bounds__(64) void attn_simple(const float* __restrict__ qk,
                                                  const float* __restrict__ v,
                                                  const int* __restrict__ st_sorted,
                                                  float* __restrict__ o4,
                                                  float* __restrict__ lse4) {
    __shared__ int posl[128];
    __shared__ double invn[128];
    int tid = threadIdx.x;   // 0..63
    int bh = blockIdx.x >> 8;
    int c  = blockIdx.x & 255;
    int r  = c >> 6;
    int pc = (c + 255) & 255;
    const int* stb = &st_sorted[(size_t)bh * 16384];
    posl[tid] = stb[c * 64 + tid];
    posl[tid + 64] = stb[pc * 64 + tid];
    __syncthreads();
    for (int u = 0; u < 2; ++u) {
        int j = tid + u * 64;
        const float* kr = &qk[((size_t)bh * 4096 + posl[j]) * 64];
        double ss = 0.0;
        for (int d2 = 0; d2 < 64; ++d2) { double x = (double)kr[d2]; ss += x * x; }
        invn[j] = 1.0 / fmax(sqrt(ss), 1e-12);
    }
    __syncthreads();

    int qi = posl[tid];
    const float* qr = &qk[((size_t)bh * 4096 + qi) * 64];
    float qreg[64];
#pragma unroll
    for (int d2 = 0; d2 < 64; ++d2) qreg[d2] = qr[d2];

    float dots[128];
    float m = -INFINITY;
    for (int j = 0; j < 128; ++j) {
        const float* kr = &qk[((size_t)bh * 4096 + posl[j]) * 64];
        double acc = 0.0;
#pragma unroll
        for (int d2 = 0; d2 < 64; ++d2) acc += (double)qreg[d2] * (double)kr[d2];
        float dd = (float)(acc * invn[j] * 0.125);
        if (qi == posl[j]) dd = -5e4f;
        dots[j] = dd;
        m = fmaxf(m, dd);
    }
    double l = 0.0;
    for (int j = 0; j < 128; ++j) {
        float e = expf(dots[j] - m);
        dots[j] = e;
        l += (double)e;
    }
    float lse = m + (float)log(l);
    lse4[((size_t)bh * 4 + r) * 4096 + qi] = lse;
    float rl = (float)(1.0 / l);

    float o[64];
#pragma unroll
    for (int d2 = 0; d2 < 64; ++d2) o[d2] = 0.f;
    for (int j = 0; j < 128; ++j) {
        const float* vr = &v[((size_t)bh * 4096 + posl[j]) * 64];
        float p = dots[j];
#pragma unroll
        for (int d2 = 0; d2 < 64; ++d2) o[d2] += p * vr[d2];
    }
    size_t ob = (((size_t)bh * 4 + r) * 4096 + qi) * 64;
#pragma unroll
    for (int d2 = 0; d2 < 64; ++d2) o4[ob + d2] = o[d2] * rl;
}

// ---------------------------------------------------------------------------
// Combine hash rounds (softmax over per-round lse). Grid 32768.
// ---------------------------------------------------------------------------
__global__ __launch_bounds__(256) void combine_kernel(const float* __restrict__ o4,
                                                      const float* __restrict__ lse4,
                                                      float* __restrict__ o_bt) {
    int tid = threadIdx.x;
    int gt = blockIdx.x * 4 + (tid >> 6);  // global token 0..131071
    int d = tid & 63;
    int bh = gt >> 12, p = gt & 4095;
    size_t base = ((size_t)bh * 4) * 4096 + p;
    float l0 = lse4[base];
    float l1 = lse4[base + 4096];
    float l2 = lse4[base + 8192];
    float l3 = lse4[base + 12288];
    float mm = fmaxf(fmaxf(l0, l1), fmaxf(l2, l3));
    float w0 = __expf(l0 - mm), w1 = __expf(l1 - mm);
    float w2 = __expf(l2 - mm), w3 = __expf(l3 - mm);
    float W = w0 + w1 + w2 + w3;
    size_t ob = (((size_t)bh * 4) * 4096 + p) * 64 + d;
    const size_t rs = (size_t)4096 * 64;
    float o = w0 * o4[ob]
            + w1 * o4[ob + rs]
            + w2 * o4[ob + 2 * rs]
            + w3 * o4[ob + 3 * rs];
    int b = bh >> 4, h = bh & 15;
    o_bt[((size_t)b * 4096 + p) * 1024 + h * 64 + d] = o / W;
}

// ---------------------------------------------------------------------------
extern "C" void kernel_launch(void* const* d_in, const int* in_sizes, int n_in,
                              void* d_out, int out_size, void* d_ws, size_t ws_size,
                              hipStream_t stream) {
    const float* x    = (const float*)d_in[0];   // queries (2,4096,1024)
    const float* Wqk  = (const float*)d_in[4];   // (1024,1024)
    const float* Wv   = (const float*)d_in[5];
    const float* Wout = (const float*)d_in[6];
    const float* bout = (const float*)d_in[7];   // (1024,)
    const float* rot  = (const float*)d_in[8];   // (64,4,32)
    float* out = (float*)d_out;

    char* ws = (char*)d_ws;
    float* qk32          = (float*)(ws);                        // 33,554,432 B (reused as o_bt)
    float* v             = (float*)(ws + 33554432);             // 33,554,432
    float* o4            = (float*)(ws + 67108864);             // 134,217,728
    float* lse4          = (float*)(ws + 201326592);            // 2,097,152
    int* keys            = (int*)(ws + 203423744);              // 2,097,152
    int* st_sorted       = (int*)(ws + 205520896);              // 2,097,152
    float* o_bt          = qk32;                                // alias: qk32 dead after attn

    proj_gemm<<<dim3(1024, 4), 256, 0, stream>>>(x, Wqk, qk32, 1, nullptr);
    proj_gemm<<<dim3(1024, 4), 256, 0, stream>>>(x, Wv, v, 1, nullptr);
    bucket32<<<2048, 256, 0, stream>>>(qk32, rot, keys);
    bitonic_kernel<<<32, 256, 0, stream>>>(keys, st_sorted);
    attn_simple<<<8192, 64, 0, stream>>>(qk32, v, st_sorted, o4, lse4);
    combine_kernel<<<32768, 256, 0, stream>>>(o4, lse4, o_bt);
    proj_gemm<<<dim3(1024, 4), 256, 0, stream>>>(o_bt, Wout, out, 0, bout);
}

// Round 6
// 1767.584 us; speedup vs baseline: 1.6846x; 1.6846x over previous
//
#include <hip/hip_runtime.h>
#include <hip/hip_bf16.h>
#include <math.h>

// B=2, N=4096, C=1024, HEADS=16, DH=64, BUCKET=64, N_HASHES=4, n_buckets=64
// BH=32, T=4096, 256 bins (r*64+b), 256 chunks of 64 slots per bh.
//
// NUMERICS CONTRACT (round 5 pass): the discrete path — qk projection and
// bucket rotation — must be an ascending-k fp32 FMA chain per output element
// (replicates the numpy fp32 reference's argmax decisions). sgemm128 below
// preserves that chain bit-for-bit (explicit fmaf, k0 ascending, kk ascending).
// bucket32 and bitonic_kernel are byte-identical to round 5.

// ---------------------------------------------------------------------------
// Tiled fp32 GEMM: C[m][n] = seqFMA_k A[m][k]*W[n][k] (+bias at end).
// headLayout=1 -> head layout (qk, v); 0 -> row-major (out).
// 128x128 tile, BK=8, 256 threads, 8x8 micro-tile. Bit-identical chain to the
// round-5 proj_gemm (single fp32 accumulator per element, k ascending, fmaf).
// ---------------------------------------------------------------------------
__global__ __launch_bounds__(256) void sgemm128(const float* __restrict__ A,
                                                const float* __restrict__ W,
                                                float* __restrict__ out,
                                                int headLayout,
                                                const float* __restrict__ bias) {
    __shared__ float As[8][128];
    __shared__ float Bs[8][128];
    int tid = threadIdx.x;
    int tx = tid & 15, ty = tid >> 4;
    int m0 = blockIdx.x * 128, n0 = blockIdx.y * 128;
    int lr = tid >> 1;
    int lk = (tid & 1) * 4;
    float acc[8][8];
#pragma unroll
    for (int i = 0; i < 8; ++i)
#pragma unroll
        for (int j = 0; j < 8; ++j) acc[i][j] = 0.f;

    for (int k0 = 0; k0 < 1024; k0 += 8) {
        float4 av = *(const float4*)&A[(size_t)(m0 + lr) * 1024 + k0 + lk];
        float4 bv = *(const float4*)&W[(size_t)(n0 + lr) * 1024 + k0 + lk];
        __syncthreads();
        As[lk + 0][lr] = av.x; As[lk + 1][lr] = av.y;
        As[lk + 2][lr] = av.z; As[lk + 3][lr] = av.w;
        Bs[lk + 0][lr] = bv.x; Bs[lk + 1][lr] = bv.y;
        Bs[lk + 2][lr] = bv.z; Bs[lk + 3][lr] = bv.w;
        __syncthreads();
#pragma unroll
        for (int kk = 0; kk < 8; ++kk) {
            float a[8], b[8];
            *(float4*)&a[0] = *(const float4*)&As[kk][tx * 8];
            *(float4*)&a[4] = *(const float4*)&As[kk][tx * 8 + 4];
            *(float4*)&b[0] = *(const float4*)&Bs[kk][ty * 8];
            *(float4*)&b[4] = *(const float4*)&Bs[kk][ty * 8 + 4];
#pragma unroll
            for (int i = 0; i < 8; ++i)
#pragma unroll
                for (int j = 0; j < 8; ++j)
                    acc[i][j] = fmaf(a[i], b[j], acc[i][j]);
        }
    }
#pragma unroll
    for (int i = 0; i < 8; ++i) {
        int m = m0 + tx * 8 + i;
        int bb = m >> 12, t = m & 4095;
#pragma unroll
        for (int j = 0; j < 8; ++j) {
            int n = n0 + ty * 8 + j;
            float val = acc[i][j];
            if (bias) val += bias[n];
            if (headLayout) {
                out[(((size_t)(bb * 16 + (n >> 6))) * 4096 + t) * 64 + (n & 63)] = val;
            } else {
                out[(size_t)m * 1024 + n] = val;
            }
        }
    }
}

// ---------------------------------------------------------------------------
// Bucketing (byte-identical to round 5): one thread per (bh, r, token).
// rotated[i] = seqFMA_f qk[f]*R[f,r,i] in fp32; argmax over [rot, -rot].
// key = (r*64+bucket)*4096 + token at slot r*4096+token.
// ---------------------------------------------------------------------------
__global__ __launch_bounds__(256) void bucket32(const float* __restrict__ qk,
                                                const float* __restrict__ rot,
                                                int* __restrict__ keys) {
    int gid = blockIdx.x * 256 + threadIdx.x;   // 0..524287
    int token = gid & 4095;
    int r = (gid >> 12) & 3;
    int bh = gid >> 14;
    const float* q = &qk[((size_t)bh * 4096 + token) * 64];
    float racc[32];
#pragma unroll
    for (int i = 0; i < 32; ++i) racc[i] = 0.f;
    for (int f = 0; f < 64; ++f) {
        float qv = q[f];
        const float* rp = &rot[f * 128 + r * 32];
#pragma unroll
        for (int i = 0; i < 32; ++i) racc[i] = fmaf(qv, rp[i], racc[i]);
    }
    float best = -INFINITY;
    int bi = 0;
#pragma unroll
    for (int i = 0; i < 32; ++i) { if (racc[i] > best) { best = racc[i]; bi = i; } }
#pragma unroll
    for (int i = 0; i < 32; ++i) { float x = -racc[i]; if (x > best) { best = x; bi = 32 + i; } }
    int bin = r * 64 + bi;
    keys[(size_t)bh * 16384 + r * 4096 + token] = bin * 4096 + token;
}

// ---------------------------------------------------------------------------
// Bitonic sort of 16384 keys per bh in LDS (byte-identical to round 5).
// ---------------------------------------------------------------------------
__global__ __launch_bounds__(256) void bitonic_kernel(const int* __restrict__ keys,
                                                      int* __restrict__ st_sorted) {
    __shared__ int s[16384];
    int bh = blockIdx.x, tid = threadIdx.x;
    for (int u = 0; u < 64; ++u)
        s[u * 256 + tid] = keys[(size_t)bh * 16384 + u * 256 + tid];
    __syncthreads();
    for (int k = 2; k <= 16384; k <<= 1) {
        for (int j = k >> 1; j > 0; j >>= 1) {
            for (int u = 0; u < 64; ++u) {
                int i = u * 256 + tid;
                int ixj = i ^ j;
                if (ixj > i) {
                    int a = s[i], b2 = s[ixj];
                    bool up = ((i & k) == 0);
                    if ((a > b2) == up) { s[i] = b2; s[ixj] = a; }
                }
            }
            __syncthreads();
        }
    }
    for (int u = 0; u < 64; ++u) {
        int slot = u * 256 + tid;
        st_sorted[(size_t)bh * 16384 + slot] = s[slot] & 4095;
    }
}

// ---------------------------------------------------------------------------
// Tiled chunked attention (r1 structure; exonerated by r3 bisect).
// Grid 8192 = 32 bh * 256 chunks. Block 256.
// dots = bq(64x64) . bk^T(128x64) * invnorm * 0.125, self-mask, softmax,
// probs @ bv -> o4 (fp32) + lse4.
// ---------------------------------------------------------------------------
__global__ __launch_bounds__(256) void attn_kernel(const float* __restrict__ qk,
                                                   const float* __restrict__ v,
                                                   const int* __restrict__ st_sorted,
                                                   float* __restrict__ o4,
                                                   float* __restrict__ lse4) {
    __shared__ float bufA[128 * 68];  // phase1: kqt[f][row] stride 132; phase2: pT[j][i] stride 68
    __shared__ float vsl[128 * 68];   // [row][c] stride 68
    __shared__ float red[64 * 17];
    __shared__ int posl[128];
    __shared__ float invl[128];

    int tid = threadIdx.x;
    int bh = blockIdx.x >> 8;
    int c = blockIdx.x & 255;
    int r = c >> 6;
    int pc = (c + 255) & 255;
    const int* stb = &st_sorted[(size_t)bh * 16384];
    if (tid < 64) posl[tid] = stb[c * 64 + tid];
    else if (tid < 128) posl[tid] = stb[pc * 64 + (tid - 64)];
    __syncthreads();

    float* kqt = bufA;
    for (int u = 0; u < 8; ++u) {
        int flat = u * 256 + tid;              // 0..2047 float4 units
        int row = flat >> 4;
        int f4 = (flat & 15) * 4;
        size_t gbase = ((size_t)bh * 4096 + posl[row]) * 64 + f4;
        float4 qv = *(const float4*)&qk[gbase];
        kqt[(f4 + 0) * 132 + row] = qv.x;
        kqt[(f4 + 1) * 132 + row] = qv.y;
        kqt[(f4 + 2) * 132 + row] = qv.z;
        kqt[(f4 + 3) * 132 + row] = qv.w;
        *(float4*)&vsl[row * 68 + f4] = *(const float4*)&v[gbase];
    }
    __syncthreads();

    if (tid < 128) {
        float ss = 0.f;
        for (int f = 0; f < 64; ++f) { float x = kqt[f * 132 + tid]; ss += x * x; }
        invl[tid] = 1.0f / fmaxf(sqrtf(ss), 1e-12f);
    }
    __syncthreads();

    int tx = tid & 15, ty = tid >> 4;   // rows i=tx*4..+4 (queries), cols j=ty*8..+8 (keys)
    float acc[4][8];
#pragma unroll
    for (int i = 0; i < 4; ++i)
#pragma unroll
        for (int j = 0; j < 8; ++j) acc[i][j] = 0.f;
    for (int f = 0; f < 64; ++f) {
        float a[4], b[8];
        *(float4*)a = *(const float4*)&kqt[f * 132 + tx * 4];
        *(float4*)&b[0] = *(const float4*)&kqt[f * 132 + ty * 8];
        *(float4*)&b[4] = *(const float4*)&kqt[f * 132 + ty * 8 + 4];
#pragma unroll
        for (int i = 0; i < 4; ++i)
#pragma unroll
            for (int j = 0; j < 8; ++j) acc[i][j] = fmaf(a[i], b[j], acc[i][j]);
    }

    // scale + self-mask
    int qp[4];
#pragma unroll
    for (int ii = 0; ii < 4; ++ii) qp[ii] = posl[tx * 4 + ii];
#pragma unroll
    for (int jj = 0; jj < 8; ++jj) {
        int j = ty * 8 + jj;
        float sc = invl[j] * 0.125f;
        int kp = posl[j];
#pragma unroll
        for (int ii = 0; ii < 4; ++ii) {
            float x = acc[ii][jj] * sc;
            acc[ii][jj] = (qp[ii] == kp) ? -5e4f : x;
        }
    }

    // row max across the 16 ty-groups
#pragma unroll
    for (int ii = 0; ii < 4; ++ii) {
        float pm = acc[ii][0];
#pragma unroll
        for (int jj = 1; jj < 8; ++jj) pm = fmaxf(pm, acc[ii][jj]);
        red[(tx * 4 + ii) * 17 + ty] = pm;
    }
    __syncthreads();
    float m[4];
#pragma unroll
    for (int ii = 0; ii < 4; ++ii) {
        float mm = red[(tx * 4 + ii) * 17 + 0];
        for (int t = 1; t < 16; ++t) mm = fmaxf(mm, red[(tx * 4 + ii) * 17 + t]);
        m[ii] = mm;
    }
    __syncthreads();  // all max reads done before red reuse + all kqt reads done before pT overwrite

    // exp, store transposed probs (unnormalized), partial sums
    float* pT = bufA;
    float ps[4] = {0.f, 0.f, 0.f, 0.f};
#pragma unroll
    for (int jj = 0; jj < 8; ++jj) {
        int j = ty * 8 + jj;
#pragma unroll
        for (int ii = 0; ii < 4; ++ii) {
            float e = __expf(acc[ii][jj] - m[ii]);
            pT[j * 68 + tx * 4 + ii] = e;
            ps[ii] += e;
        }
    }
#pragma unroll
    for (int ii = 0; ii < 4; ++ii) red[(tx * 4 + ii) * 17 + ty] = ps[ii];
    __syncthreads();
    float l[4];
#pragma unroll
    for (int ii = 0; ii < 4; ++ii) {
        float s = 0.f;
        for (int t = 0; t < 16; ++t) s += red[(tx * 4 + ii) * 17 + t];
        l[ii] = s;
    }

    if (ty == 0) {
#pragma unroll
        for (int ii = 0; ii < 4; ++ii) {
            int i = tx * 4 + ii;
            lse4[((size_t)bh * 4 + r) * 4096 + posl[i]] = m[ii] + __logf(l[ii]);
        }
    }

    // PV: rows i=tx*4..+4, cols c=ty*4..+4, K=128
    float acc2[4][4];
#pragma unroll
    for (int i = 0; i < 4; ++i)
#pragma unroll
        for (int j = 0; j < 4; ++j) acc2[i][j] = 0.f;
    for (int j = 0; j < 128; ++j) {
        float a[4], b[4];
        *(float4*)a = *(const float4*)&pT[j * 68 + tx * 4];
        *(float4*)b = *(const float4*)&vsl[j * 68 + ty * 4];
#pragma unroll
        for (int ii = 0; ii < 4; ++ii)
#pragma unroll
            for (int cc = 0; cc < 4; ++cc) acc2[ii][cc] = fmaf(a[ii], b[cc], acc2[ii][cc]);
    }
#pragma unroll
    for (int ii = 0; ii < 4; ++ii) {
        int i = tx * 4 + ii;
        float rl = 1.0f / l[ii];
        size_t ob = (((size_t)bh * 4 + r) * 4096 + posl[i]) * 64 + ty * 4;
        float4 ov;
        ov.x = acc2[ii][0] * rl;
        ov.y = acc2[ii][1] * rl;
        ov.z = acc2[ii][2] * rl;
        ov.w = acc2[ii][3] * rl;
        *(float4*)&o4[ob] = ov;
    }
}

// ---------------------------------------------------------------------------
// Combine hash rounds (softmax over per-round lse). Grid 32768.
// ---------------------------------------------------------------------------
__global__ __launch_bounds__(256) void combine_kernel(const float* __restrict__ o4,
                                                      const float* __restrict__ lse4,
                                                      float* __restrict__ o_bt) {
    int tid = threadIdx.x;
    int gt = blockIdx.x * 4 + (tid >> 6);  // global token 0..131071
    int d = tid & 63;
    int bh = gt >> 12, p = gt & 4095;
    size_t base = ((size_t)bh * 4) * 4096 + p;
    float l0 = lse4[base];
    float l1 = lse4[base + 4096];
    float l2 = lse4[base + 8192];
    float l3 = lse4[base + 12288];
    float mm = fmaxf(fmaxf(l0, l1), fmaxf(l2, l3));
    float w0 = __expf(l0 - mm), w1 = __expf(l1 - mm);
    float w2 = __expf(l2 - mm), w3 = __expf(l3 - mm);
    float W = w0 + w1 + w2 + w3;
    size_t ob = (((size_t)bh * 4) * 4096 + p) * 64 + d;
    const size_t rs = (size_t)4096 * 64;
    float o = w0 * o4[ob]
            + w1 * o4[ob + rs]
            + w2 * o4[ob + 2 * rs]
            + w3 * o4[ob + 3 * rs];
    int b = bh >> 4, h = bh & 15;
    o_bt[((size_t)b * 4096 + p) * 1024 + h * 64 + d] = o / W;
}

// ---------------------------------------------------------------------------
extern "C" void kernel_launch(void* const* d_in, const int* in_sizes, int n_in,
                              void* d_out, int out_size, void* d_ws, size_t ws_size,
                              hipStream_t stream) {
    const float* x    = (const float*)d_in[0];   // queries (2,4096,1024)
    const float* Wqk  = (const float*)d_in[4];   // (1024,1024)
    const float* Wv   = (const float*)d_in[5];
    const float* Wout = (const float*)d_in[6];
    const float* bout = (const float*)d_in[7];   // (1024,)
    const float* rot  = (const float*)d_in[8];   // (64,4,32)
    float* out = (float*)d_out;

    char* ws = (char*)d_ws;
    float* qk32          = (float*)(ws);                        // 33,554,432 B (reused as o_bt)
    float* v             = (float*)(ws + 33554432);             // 33,554,432
    float* o4            = (float*)(ws + 67108864);             // 134,217,728
    float* lse4          = (float*)(ws + 201326592);            // 2,097,152
    int* keys            = (int*)(ws + 203423744);              // 2,097,152
    int* st_sorted       = (int*)(ws + 205520896);              // 2,097,152
    float* o_bt          = qk32;                                // alias: qk32 dead after attn

    sgemm128<<<dim3(64, 8), 256, 0, stream>>>(x, Wqk, qk32, 1, nullptr);
    sgemm128<<<dim3(64, 8), 256, 0, stream>>>(x, Wv, v, 1, nullptr);
    bucket32<<<2048, 256, 0, stream>>>(qk32, rot, keys);
    bitonic_kernel<<<32, 256, 0, stream>>>(keys, st_sorted);
    attn_kernel<<<8192, 256, 0, stream>>>(qk32, v, st_sorted, o4, lse4);
    combine_kernel<<<32768, 256, 0, stream>>>(o4, lse4, o_bt);
    sgemm128<<<dim3(64, 8), 256, 0, stream>>>(o_bt, Wout, out, 0, bout);
}